// Round 7
// baseline (5627.198 us; speedup 1.0000x reference)
//
#include <hip/hip_runtime.h>
#include <hip/hip_cooperative_groups.h>
#include <math.h>

namespace cg = cooperative_groups;

#define N 1024
#define D 512
#define NIT 200
#define PIT 50

typedef __attribute__((ext_vector_type(8))) short short8;
typedef __attribute__((ext_vector_type(4))) float floatx4;

// ---------------- helpers ----------------
__device__ __forceinline__ float wave_reduce(float v) {
#pragma unroll
  for (int off = 32; off; off >>= 1) v += __shfl_xor(v, off, 64);
  return v;
}

__device__ __forceinline__ unsigned short f2bf(float x) {
  unsigned int u = __float_as_uint(x);
  u += 0x7FFF + ((u >> 16) & 1);  // round-to-nearest-even
  return (unsigned short)(u >> 16);
}
__device__ __forceinline__ float bf2f(unsigned short h) {
  return __uint_as_float(((unsigned int)h) << 16);
}

// async global->LDS, 16 B per lane; LDS dest must be lane-contiguous
#define GLD16(g, l)                                                     \
  __builtin_amdgcn_global_load_lds(                                     \
      (__attribute__((address_space(1))) void*)(g),                     \
      (__attribute__((address_space(3))) void*)(l), 16, 0, 0)

// Interleaved hi/lo format: logical [row][1024] bf16-pairs stored as 128
// chunks of 32 B per row: [8 hi shorts][8 lo shorts]. Row = 2048 shorts.
// Staging slot mapping for one 64-row x 32-k tile (idx in [0,512) 16B slots):
__device__ __forceinline__ size_t stage_off(int idx, int base, int kbase) {
  int s32 = idx >> 1, hh = idx & 1;
  int rp = s32 >> 3;                    // row pair 0..31
  int pp = (s32 & 7) ^ (rp & 7);        // un-swizzled slot within 256B line
  int srow = rp * 2 + (pp >> 2);
  int skc = pp & 3;
  return (size_t)(base + srow) * 2048 + (size_t)(kbase >> 3) * 16 +
         (size_t)skc * 16 + (size_t)hh * 8;  // in shorts
}

// ---------------- row normalize ----------------
__global__ __launch_bounds__(256) void normalize_k(
    const float* __restrict__ f1, const float* __restrict__ f2,
    float* __restrict__ Yn, float* __restrict__ An) {
  int b = blockIdx.x;
  const float* src;
  float* dst;
  if (b < N) { src = f1 + (size_t)b * D; dst = Yn + (size_t)b * D; }
  else       { src = f2 + (size_t)(b - N) * D; dst = An + (size_t)(b - N) * D; }
  int tid = threadIdx.x;
  float2 e = ((const float2*)src)[tid];
  float ss = e.x * e.x + e.y * e.y;
  ss = wave_reduce(ss);
  __shared__ float sh[4];
  int lane = tid & 63, wid = tid >> 6;
  if (lane == 0) sh[wid] = ss;
  __syncthreads();
  float total = sh[0] + sh[1] + sh[2] + sh[3];
  float rn = 1.0f / sqrtf(total);
  ((float2*)dst)[tid] = make_float2(e.x * rn, e.y * rn);
}

// ---------------- fp32 NT GEMM (one-time uses: M, YAt, final P) ----------------
#define LDT 68
__global__ __launch_bounds__(256) void gemm_nt(
    const float* __restrict__ A, int lda,
    const float* __restrict__ B, int ldb,
    float* __restrict__ C, int ldc, int K) {
  __shared__ __align__(16) float At[32][LDT];
  __shared__ __align__(16) float Bt[32][LDT];
  const int tid = threadIdx.x;
  const int rowBase = blockIdx.y * 64;
  const int colBase = blockIdx.x * 64;
  const int tx = tid & 15, ty = tid >> 4;
  float acc[4][4] = {};
  const int r0 = tid >> 3;
  const int r1 = r0 + 32;
  const int kc = (tid & 7) * 4;

  for (int k0 = 0; k0 < K; k0 += 32) {
    __syncthreads();
    {
      float4 av = *(const float4*)(A + (size_t)(rowBase + r0) * lda + k0 + kc);
      At[kc + 0][r0] = av.x; At[kc + 1][r0] = av.y; At[kc + 2][r0] = av.z; At[kc + 3][r0] = av.w;
      float4 bv = *(const float4*)(B + (size_t)(colBase + r0) * ldb + k0 + kc);
      Bt[kc + 0][r0] = bv.x; Bt[kc + 1][r0] = bv.y; Bt[kc + 2][r0] = bv.z; Bt[kc + 3][r0] = bv.w;
      av = *(const float4*)(A + (size_t)(rowBase + r1) * lda + k0 + kc);
      At[kc + 0][r1] = av.x; At[kc + 1][r1] = av.y; At[kc + 2][r1] = av.z; At[kc + 3][r1] = av.w;
      bv = *(const float4*)(B + (size_t)(colBase + r1) * ldb + k0 + kc);
      Bt[kc + 0][r1] = bv.x; Bt[kc + 1][r1] = bv.y; Bt[kc + 2][r1] = bv.z; Bt[kc + 3][r1] = bv.w;
    }
    __syncthreads();
#pragma unroll
    for (int kk = 0; kk < 32; ++kk) {
      float4 a4 = *(const float4*)&At[kk][ty * 4];
      float4 b4 = *(const float4*)&Bt[kk][tx * 4];
      float a[4] = {a4.x, a4.y, a4.z, a4.w};
      float b[4] = {b4.x, b4.y, b4.z, b4.w};
#pragma unroll
      for (int r = 0; r < 4; ++r)
#pragma unroll
        for (int c = 0; c < 4; ++c) acc[r][c] = fmaf(a[r], b[c], acc[r][c]);
    }
  }
#pragma unroll
  for (int r = 0; r < 4; ++r) {
    int i = rowBase + ty * 4 + r;
    size_t off = (size_t)i * ldc + colBase + tx * 4;
    *(float4*)(C + off) = make_float4(acc[r][0], acc[r][1], acc[r][2], acc[r][3]);
  }
}

// ================= persistent cooperative kernel ==============================
// 512 blocks x 256 threads, 32 KB LDS -> 2 blocks/CU under any accounting.
// Interleaved hi/lo staging + paired-row XOR LDS layout => 2-way (free) banks.
__global__ __launch_bounds__(256, 2) void fista_persistent(
    const float* __restrict__ Mm,
    unsigned short* __restrict__ Zint, unsigned short* __restrict__ Mint,
    const float* __restrict__ YAt,
    float* __restrict__ Vp0, float* __restrict__ Vp1,
    float* __restrict__ vb,     // 3*N floats: v ping, v pong, w
    float* __restrict__ stepP,  // 1 float
    float* __restrict__ Xg) {
  cg::grid_group grid = cg::this_grid();
  // per matrix per k-tile: 64 rows x 32 k x (hi+lo) = 4096 shorts = 8 KB
  __shared__ __align__(16) unsigned short sA[2][4096], sB[2][4096];
  float* shred = (float*)&sB[1][0];  // reduction scratch (dead between GEMMs)

  const int tid = threadIdx.x;
  const int b = blockIdx.x;
  const int lane = tid & 63, wv = tid >> 6;

  // ---- prologue: split M into interleaved bf16 hi/lo ----
  {
    size_t e = ((size_t)b * 2048) + (size_t)tid * 8;
    int row = (int)(e >> 10);
    int cl = (int)((e & 1023) >> 3);
    float4 m0 = *(const float4*)(Mm + e);
    float4 m1 = *(const float4*)(Mm + e + 4);
    ushort4 h0, l0, h1, l1;
    h0.x = f2bf(m0.x); l0.x = f2bf(m0.x - bf2f(h0.x));
    h0.y = f2bf(m0.y); l0.y = f2bf(m0.y - bf2f(h0.y));
    h0.z = f2bf(m0.z); l0.z = f2bf(m0.z - bf2f(h0.z));
    h0.w = f2bf(m0.w); l0.w = f2bf(m0.w - bf2f(h0.w));
    h1.x = f2bf(m1.x); l1.x = f2bf(m1.x - bf2f(h1.x));
    h1.y = f2bf(m1.y); l1.y = f2bf(m1.y - bf2f(h1.y));
    h1.z = f2bf(m1.z); l1.z = f2bf(m1.z - bf2f(h1.z));
    h1.w = f2bf(m1.w); l1.w = f2bf(m1.w - bf2f(h1.w));
    unsigned short* dst = Mint + (size_t)row * 2048 + (size_t)cl * 16;
    *(ushort4*)(dst) = h0;     *(ushort4*)(dst + 4) = h1;
    *(ushort4*)(dst + 8) = l0; *(ushort4*)(dst + 12) = l1;
  }

  // ---- init X/Z register rows + Zint global + power vector ----
  const int row0 = 2 * b, row1 = row0 + 1;
  const float cinit = 1.0f / (float)N;
  float4 Xr[2], Zr[2], Ya[2];
  Xr[0] = make_float4(cinit, cinit, cinit, cinit);
  Xr[1] = Xr[0]; Zr[0] = Xr[0]; Zr[1] = Xr[0];
  Ya[0] = ((const float4*)(YAt + (size_t)row0 * N))[tid];
  Ya[1] = ((const float4*)(YAt + (size_t)row1 * N))[tid];
  {
    unsigned short zh = f2bf(cinit);  // 2^-10 exact
    ushort4 z4; z4.x = zh; z4.y = zh; z4.z = zh; z4.w = zh;
    ushort4 z0; z0.x = 0; z0.y = 0; z0.z = 0; z0.w = 0;
    const int zo = (tid >> 1) * 16 + (tid & 1) * 4;
    *(ushort4*)(Zint + (size_t)row0 * 2048 + zo) = z4;
    *(ushort4*)(Zint + (size_t)row0 * 2048 + zo + 8) = z0;
    *(ushort4*)(Zint + (size_t)row1 * 2048 + zo) = z4;
    *(ushort4*)(Zint + (size_t)row1 * 2048 + zo + 8) = z0;
    if (b == 0) ((float4*)vb)[tid] = make_float4(cinit, cinit, cinit, cinit);
  }
  grid.sync();

  // ---- power iteration: per-step normalization folded into 1/8 scale ----
  int cur = 0;
  for (int i = 0; i < PIT; ++i) {
    if (tid < 128) {
      int row = row0 + (tid >> 6);
      const float* mr = Mm + (size_t)row * N;
      const float* v = vb + cur * N;
      float s = 0.0f;
#pragma unroll
      for (int j = 0; j < N; j += 64) s = fmaf(mr[j + lane], v[j + lane], s);
      s = wave_reduce(s);
      if (lane == 0) vb[(cur ^ 1) * N + row] = s * 0.125f;
    }
    cur ^= 1;
    grid.sync();
  }
  if (tid < 128) {  // final unscaled matvec into w
    int row = row0 + (tid >> 6);
    const float* mr = Mm + (size_t)row * N;
    const float* v = vb + cur * N;
    float s = 0.0f;
#pragma unroll
    for (int j = 0; j < N; j += 64) s = fmaf(mr[j + lane], v[j + lane], s);
    s = wave_reduce(s);
    if (lane == 0) vb[2 * N + row] = s;
  }
  grid.sync();
  if (b == 0) {  // Rayleigh -> step
    const float* u = vb + cur * N;
    const float* w = vb + 2 * N;
    float r1 = 0.0f, r2 = 0.0f;
    for (int j = tid; j < N; j += 256) {
      float uu = u[j];
      r1 = fmaf(uu, w[j], r1);
      r2 = fmaf(uu, uu, r2);
    }
    r1 = wave_reduce(r1);
    r2 = wave_reduce(r2);
    if (lane == 0) { shred[wv] = r1; shred[4 + wv] = r2; }
    __syncthreads();
    if (tid == 0) {
      float R1 = shred[0] + shred[1] + shred[2] + shred[3];
      float R2 = shred[4] + shred[5] + shred[6] + shred[7];
      stepP[0] = 1.0f / (2.0f * (R1 / R2) + 1e-8f);
    }
  }
  grid.sync();
  const float c2 = 2.0f * stepP[0];

  // ---- GEMM tile geometry (XCD swizzle, validated round 4) ----
  const int xcd = b & 7;
  const int jj = b >> 3;
  const int zzK = xcd & 1;
  const int rowBase = (((xcd >> 1) << 2) + (jj >> 4)) * 64;
  const int colBase = (jj & 15) * 64;
  const int kbase = zzK * 512;
  const int wr = (wv >> 1) * 32, wc = (wv & 1) * 32;
  const int q = lane >> 4, m = lane & 15;
  const size_t ga0 = stage_off(tid, rowBase, kbase);
  const size_t ga1 = stage_off(tid + 256, rowBase, kbase);
  const size_t gb0 = stage_off(tid, colBase, kbase);
  const size_t gb1 = stage_off(tid + 256, colBase, kbase);
  float* Vpout = zzK ? Vp1 : Vp0;

  // ko advances 64 shorts (= 4 chunks of 32B) per k-tile of 32
#define ISSUE(buf, ko)                                         \
  do {                                                         \
    GLD16(Zint + ga0 + (ko), &sA[buf][tid * 8]);               \
    GLD16(Zint + ga1 + (ko), &sA[buf][(256 + tid) * 8]);       \
    GLD16(Mint + gb0 + (ko), &sB[buf][tid * 8]);               \
    GLD16(Mint + gb1 + (ko), &sB[buf][(256 + tid) * 8]);       \
  } while (0)

  // ---- FISTA main loop ----
  float tmom = 1.0f;
  for (int it = 0; it < NIT; ++it) {
    // ===== GEMM phase: partial (Z@M) for this tile & K-half =====
    floatx4 acc[2][2];
#pragma unroll
    for (int t = 0; t < 2; ++t)
#pragma unroll
      for (int u = 0; u < 2; ++u) acc[t][u] = (floatx4){0.f, 0.f, 0.f, 0.f};

    ISSUE(0, 0);
    __syncthreads();
    for (int kt = 0; kt < 16; ++kt) {  // 16 k-tiles of 32
      const int curb = kt & 1;
      if (kt + 1 < 16) ISSUE(curb ^ 1, (kt + 1) * 64);
      short8 ah[2], al[2], bh[2], bl[2];
#pragma unroll
      for (int t = 0; t < 2; ++t) {
        int ar = wr + t * 16 + m;
        int la = ar >> 1;
        int offa = la * 128 + (((q + ((ar & 1) << 2)) ^ (la & 7)) << 4);
        ah[t] = *(const short8*)&sA[curb][offa];
        al[t] = *(const short8*)&sA[curb][offa + 8];
        int br = wc + t * 16 + m;
        int lb = br >> 1;
        int offb = lb * 128 + (((q + ((br & 1) << 2)) ^ (lb & 7)) << 4);
        bh[t] = *(const short8*)&sB[curb][offb];
        bl[t] = *(const short8*)&sB[curb][offb + 8];
      }
#pragma unroll
      for (int t = 0; t < 2; ++t)
#pragma unroll
        for (int u = 0; u < 2; ++u) {
          acc[t][u] = __builtin_amdgcn_mfma_f32_16x16x32_bf16(ah[t], bh[u], acc[t][u], 0, 0, 0);
          acc[t][u] = __builtin_amdgcn_mfma_f32_16x16x32_bf16(ah[t], bl[u], acc[t][u], 0, 0, 0);
          acc[t][u] = __builtin_amdgcn_mfma_f32_16x16x32_bf16(al[t], bh[u], acc[t][u], 0, 0, 0);
        }
      __syncthreads();
    }
    // store raw partials; C/D layout col = lane&15, row = (lane>>4)*4 + reg
#pragma unroll
    for (int t = 0; t < 2; ++t) {
      int rowb = rowBase + wr + t * 16 + q * 4;
#pragma unroll
      for (int u = 0; u < 2; ++u) {
        int col = colBase + wc + u * 16 + m;
#pragma unroll
        for (int r = 0; r < 4; ++r)
          Vpout[(size_t)(rowb + r) * N + col] = acc[t][u][r];
      }
    }
    grid.sync();

    // ===== update phase: rows 2b, 2b+1 (X/Z/Ya in registers) =====
    float tn = 0.5f * (1.0f + sqrtf(1.0f + 4.0f * tmom * tmom));
    float mom = (tmom - 1.0f) / tn;
    tmom = tn;
#pragma unroll
    for (int r = 0; r < 2; ++r) {
      const int row = row0 + r;
      float4 a0 = ((const float4*)(Vp0 + (size_t)row * N))[tid];
      float4 a1 = ((const float4*)(Vp1 + (size_t)row * N))[tid];
      float vl[4];
      vl[0] = Zr[r].x - c2 * (a0.x + a1.x - Ya[r].x);
      vl[1] = Zr[r].y - c2 * (a0.y + a1.y - Ya[r].y);
      vl[2] = Zr[r].z - c2 * (a0.z + a1.z - Ya[r].z);
      vl[3] = Zr[r].w - c2 * (a0.w + a1.w - Ya[r].w);

      float s = vl[0] + vl[1] + vl[2] + vl[3];
      s = wave_reduce(s);
      __syncthreads();
      if (lane == 0) shred[wv] = s;
      __syncthreads();
      float theta = (shred[0] + shred[1] + shred[2] + shred[3] - 1.0f) * (1.0f / (float)N);
      for (int itr = 0; itr < 40; ++itr) {  // Michelot fixed point (exact proj)
        float sa = 0.0f, ka = 0.0f;
#pragma unroll
        for (int j = 0; j < 4; ++j)
          if (vl[j] > theta) { sa += vl[j]; ka += 1.0f; }
        sa = wave_reduce(sa);
        ka = wave_reduce(ka);
        __syncthreads();
        if (lane == 0) { shred[wv] = sa; shred[4 + wv] = ka; }
        __syncthreads();
        float SA = shred[0] + shred[1] + shred[2] + shred[3];
        float KA = fmaxf(shred[4] + shred[5] + shred[6] + shred[7], 1.0f);
        float tnn = (SA - 1.0f) / KA;
        bool done = (tnn - theta) <= (1e-7f * fabsf(tnn) + 1e-12f);
        theta = tnn;
        if (done) break;
      }
      float xo[4] = {Xr[r].x, Xr[r].y, Xr[r].z, Xr[r].w};
      float xn[4], zn[4];
#pragma unroll
      for (int j = 0; j < 4; ++j) {
        xn[j] = fmaxf(vl[j] - theta, 0.0f);
        zn[j] = xn[j] + mom * (xn[j] - xo[j]);
      }
      Xr[r] = make_float4(xn[0], xn[1], xn[2], xn[3]);
      Zr[r] = make_float4(zn[0], zn[1], zn[2], zn[3]);
      ushort4 zh4, zl4;
      zh4.x = f2bf(zn[0]); zl4.x = f2bf(zn[0] - bf2f(zh4.x));
      zh4.y = f2bf(zn[1]); zl4.y = f2bf(zn[1] - bf2f(zh4.y));
      zh4.z = f2bf(zn[2]); zl4.z = f2bf(zn[2] - bf2f(zh4.z));
      zh4.w = f2bf(zn[3]); zl4.w = f2bf(zn[3] - bf2f(zh4.w));
      unsigned short* dz =
          Zint + (size_t)row * 2048 + (tid >> 1) * 16 + (tid & 1) * 4;
      *(ushort4*)dz = zh4;
      *(ushort4*)(dz + 8) = zl4;
    }
    grid.sync();
  }
#undef ISSUE

  ((float4*)(Xg + (size_t)row0 * N))[tid] = Xr[0];
  ((float4*)(Xg + (size_t)row1 * N))[tid] = Xr[1];
}

// ================= fallback path (interleaved variants) =======================
__global__ __launch_bounds__(256) void split_int_k(
    const float* __restrict__ Mm, unsigned short* __restrict__ Mint) {
  size_t e = ((size_t)blockIdx.x * 2048) + (size_t)threadIdx.x * 8;
  int row = (int)(e >> 10);
  int cl = (int)((e & 1023) >> 3);
  float4 m0 = *(const float4*)(Mm + e);
  float4 m1 = *(const float4*)(Mm + e + 4);
  ushort4 h0, l0, h1, l1;
  h0.x = f2bf(m0.x); l0.x = f2bf(m0.x - bf2f(h0.x));
  h0.y = f2bf(m0.y); l0.y = f2bf(m0.y - bf2f(h0.y));
  h0.z = f2bf(m0.z); l0.z = f2bf(m0.z - bf2f(h0.z));
  h0.w = f2bf(m0.w); l0.w = f2bf(m0.w - bf2f(h0.w));
  h1.x = f2bf(m1.x); l1.x = f2bf(m1.x - bf2f(h1.x));
  h1.y = f2bf(m1.y); l1.y = f2bf(m1.y - bf2f(h1.y));
  h1.z = f2bf(m1.z); l1.z = f2bf(m1.z - bf2f(h1.z));
  h1.w = f2bf(m1.w); l1.w = f2bf(m1.w - bf2f(h1.w));
  unsigned short* dst = Mint + (size_t)row * 2048 + (size_t)cl * 16;
  *(ushort4*)(dst) = h0;     *(ushort4*)(dst + 4) = h1;
  *(ushort4*)(dst + 8) = l0; *(ushort4*)(dst + 12) = l1;
}

__global__ __launch_bounds__(256) void init_int_k(
    float* __restrict__ X, unsigned short* __restrict__ Zint,
    float* __restrict__ v) {
  int row = blockIdx.x, tid = threadIdx.x;
  const float c = 1.0f / (float)N;
  ((float4*)(X + (size_t)row * N))[tid] = make_float4(c, c, c, c);
  unsigned short zh = f2bf(c);
  ushort4 z4; z4.x = zh; z4.y = zh; z4.z = zh; z4.w = zh;
  ushort4 z0; z0.x = 0; z0.y = 0; z0.z = 0; z0.w = 0;
  unsigned short* dz = Zint + (size_t)row * 2048 + (tid >> 1) * 16 + (tid & 1) * 4;
  *(ushort4*)dz = z4;
  *(ushort4*)(dz + 8) = z0;
  if (row == 0 && tid < N / 4) ((float4*)v)[tid] = make_float4(c, c, c, c);
}

__global__ __launch_bounds__(256) void matvec_k(
    const float* __restrict__ Mm, const float* __restrict__ v,
    float* __restrict__ w, float scale) {
  int tid = threadIdx.x;
  int lane = tid & 63, wid = tid >> 6;
  int row = blockIdx.x * 4 + wid;
  const float* mr = Mm + (size_t)row * N;
  float s = 0.0f;
#pragma unroll
  for (int j = 0; j < N; j += 64) s = fmaf(mr[j + lane], v[j + lane], s);
  s = wave_reduce(s);
  if (lane == 0) w[row] = s * scale;
}

__global__ __launch_bounds__(256) void rayleigh_k(
    const float* __restrict__ u, const float* __restrict__ w,
    float* __restrict__ stepOut) {
  int tid = threadIdx.x;
  float r1 = 0.0f, r2 = 0.0f;
  for (int j = tid; j < N; j += 256) {
    float uu = u[j];
    r1 = fmaf(uu, w[j], r1);
    r2 = fmaf(uu, uu, r2);
  }
  r1 = wave_reduce(r1);
  r2 = wave_reduce(r2);
  __shared__ float sh[8];
  int lane = tid & 63, wid = tid >> 6;
  if (lane == 0) { sh[wid] = r1; sh[4 + wid] = r2; }
  __syncthreads();
  if (tid == 0) {
    float R1 = sh[0] + sh[1] + sh[2] + sh[3];
    float R2 = sh[4] + sh[5] + sh[6] + sh[7];
    stepOut[0] = 1.0f / (2.0f * (R1 / R2) + 1e-8f);
  }
}

__global__ __launch_bounds__(256, 2) void fista_gemm_fb(
    const unsigned short* __restrict__ Zint,
    const unsigned short* __restrict__ Mint,
    float* __restrict__ Vp) {
  __shared__ __align__(16) unsigned short sA[2][4096], sB[2][4096];
  const int tid = threadIdx.x;
  const int g = blockIdx.x + (blockIdx.y << 4) + (blockIdx.z << 8);
  const int xcd = g & 7;
  const int jj = g >> 3;
  const int zz = xcd & 1;
  const int rowBase = (((xcd >> 1) << 2) + (jj >> 4)) * 64;
  const int colBase = (jj & 15) * 64;
  const int kbase = zz * 512;
  const int lane = tid & 63;
  const int wv = tid >> 6;
  const int wr = (wv >> 1) * 32, wc = (wv & 1) * 32;
  const int q = lane >> 4, m = lane & 15;

  floatx4 acc[2][2];
#pragma unroll
  for (int t = 0; t < 2; ++t)
#pragma unroll
    for (int u = 0; u < 2; ++u) acc[t][u] = (floatx4){0.f, 0.f, 0.f, 0.f};

  const size_t ga0 = stage_off(tid, rowBase, kbase);
  const size_t ga1 = stage_off(tid + 256, rowBase, kbase);
  const size_t gb0 = stage_off(tid, colBase, kbase);
  const size_t gb1 = stage_off(tid + 256, colBase, kbase);

#define ISSUEF(buf, ko)                                        \
  do {                                                         \
    GLD16(Zint + ga0 + (ko), &sA[buf][tid * 8]);               \
    GLD16(Zint + ga1 + (ko), &sA[buf][(256 + tid) * 8]);       \
    GLD16(Mint + gb0 + (ko), &sB[buf][tid * 8]);               \
    GLD16(Mint + gb1 + (ko), &sB[buf][(256 + tid) * 8]);       \
  } while (0)

  ISSUEF(0, 0);
  __syncthreads();
  for (int kt = 0; kt < 16; ++kt) {
    const int curb = kt & 1;
    if (kt + 1 < 16) ISSUEF(curb ^ 1, (kt + 1) * 64);
    short8 ah[2], al[2], bh[2], bl[2];
#pragma unroll
    for (int t = 0; t < 2; ++t) {
      int ar = wr + t * 16 + m;
      int la = ar >> 1;
      int offa = la * 128 + (((q + ((ar & 1) << 2)) ^ (la & 7)) << 4);
      ah[t] = *(const short8*)&sA[curb][offa];
      al[t] = *(const short8*)&sA[curb][offa + 8];
      int br = wc + t * 16 + m;
      int lb = br >> 1;
      int offb = lb * 128 + (((q + ((br & 1) << 2)) ^ (lb & 7)) << 4);
      bh[t] = *(const short8*)&sB[curb][offb];
      bl[t] = *(const short8*)&sB[curb][offb + 8];
    }
#pragma unroll
    for (int t = 0; t < 2; ++t)
#pragma unroll
      for (int u = 0; u < 2; ++u) {
        acc[t][u] = __builtin_amdgcn_mfma_f32_16x16x32_bf16(ah[t], bh[u], acc[t][u], 0, 0, 0);
        acc[t][u] = __builtin_amdgcn_mfma_f32_16x16x32_bf16(ah[t], bl[u], acc[t][u], 0, 0, 0);
        acc[t][u] = __builtin_amdgcn_mfma_f32_16x16x32_bf16(al[t], bh[u], acc[t][u], 0, 0, 0);
      }
    __syncthreads();
  }
#undef ISSUEF

  float* out = Vp + (size_t)zz * N * N;
#pragma unroll
  for (int t = 0; t < 2; ++t) {
    int rowb = rowBase + wr + t * 16 + q * 4;
#pragma unroll
    for (int u = 0; u < 2; ++u) {
      int col = colBase + wc + u * 16 + m;
#pragma unroll
      for (int r = 0; r < 4; ++r)
        out[(size_t)(rowb + r) * N + col] = acc[t][u][r];
    }
  }
}

__global__ __launch_bounds__(256) void fista_update_fb(
    const float* __restrict__ Vp0, const float* __restrict__ Vp1,
    const float* __restrict__ YAt, const float* __restrict__ stepPtr,
    float* __restrict__ X, unsigned short* __restrict__ Zint, float mom) {
  __shared__ float sh[8];
  const int r = blockIdx.x, tid = threadIdx.x;
  const int lane = tid & 63, wid = tid >> 6;
  const float c2 = 2.0f * stepPtr[0];
  float4 a0 = ((const float4*)(Vp0 + (size_t)r * N))[tid];
  float4 a1 = ((const float4*)(Vp1 + (size_t)r * N))[tid];
  float4 ya = ((const float4*)(YAt + (size_t)r * N))[tid];
  unsigned short* dz = Zint + (size_t)r * 2048 + (tid >> 1) * 16 + (tid & 1) * 4;
  ushort4 zh4 = *(ushort4*)dz;
  ushort4 zl4 = *(ushort4*)(dz + 8);
  float vl[4];
  vl[0] = bf2f(zh4.x) + bf2f(zl4.x) - c2 * (a0.x + a1.x - ya.x);
  vl[1] = bf2f(zh4.y) + bf2f(zl4.y) - c2 * (a0.y + a1.y - ya.y);
  vl[2] = bf2f(zh4.z) + bf2f(zl4.z) - c2 * (a0.z + a1.z - ya.z);
  vl[3] = bf2f(zh4.w) + bf2f(zl4.w) - c2 * (a0.w + a1.w - ya.w);

  float s = vl[0] + vl[1] + vl[2] + vl[3];
  s = wave_reduce(s);
  if (lane == 0) sh[wid] = s;
  __syncthreads();
  float theta = (sh[0] + sh[1] + sh[2] + sh[3] - 1.0f) * (1.0f / (float)N);
  for (int it = 0; it < 40; ++it) {
    float sa = 0.0f, ka = 0.0f;
#pragma unroll
    for (int j = 0; j < 4; ++j)
      if (vl[j] > theta) { sa += vl[j]; ka += 1.0f; }
    sa = wave_reduce(sa);
    ka = wave_reduce(ka);
    __syncthreads();
    if (lane == 0) { sh[wid] = sa; sh[4 + wid] = ka; }
    __syncthreads();
    float SA = sh[0] + sh[1] + sh[2] + sh[3];
    float KA = fmaxf(sh[4] + sh[5] + sh[6] + sh[7], 1.0f);
    float tn = (SA - 1.0f) / KA;
    bool done = (tn - theta) <= (1e-7f * fabsf(tn) + 1e-12f);
    theta = tn;
    if (done) break;
  }
  float4 x4 = ((const float4*)(X + (size_t)r * N))[tid];
  float xo[4] = {x4.x, x4.y, x4.z, x4.w};
  float xn[4], zn[4];
#pragma unroll
  for (int j = 0; j < 4; ++j) {
    xn[j] = fmaxf(vl[j] - theta, 0.0f);
    zn[j] = xn[j] + mom * (xn[j] - xo[j]);
  }
  ((float4*)(X + (size_t)r * N))[tid] = make_float4(xn[0], xn[1], xn[2], xn[3]);
  ushort4 zh, zl;
  zh.x = f2bf(zn[0]); zl.x = f2bf(zn[0] - bf2f(zh.x));
  zh.y = f2bf(zn[1]); zl.y = f2bf(zn[1] - bf2f(zh.y));
  zh.z = f2bf(zn[2]); zl.z = f2bf(zn[2] - bf2f(zh.z));
  zh.w = f2bf(zn[3]); zl.w = f2bf(zn[3] - bf2f(zh.w));
  *(ushort4*)dz = zh;
  *(ushort4*)(dz + 8) = zl;
}

// ---------------- transpose / cosine / mean ----------------
__global__ void transpose_k(const float* __restrict__ An, float* __restrict__ AnT) {
  __shared__ float t[32][33];
  int x = blockIdx.x * 32 + threadIdx.x;
  int y0 = blockIdx.y * 32;
#pragma unroll
  for (int j = 0; j < 32; j += 8)
    t[threadIdx.y + j][threadIdx.x] = An[(size_t)(y0 + threadIdx.y + j) * D + x];
  __syncthreads();
  int xo = y0 + threadIdx.x;
  int yo0 = blockIdx.x * 32;
#pragma unroll
  for (int j = 0; j < 32; j += 8)
    AnT[(size_t)(yo0 + threadIdx.y + j) * N + xo] = t[threadIdx.x][threadIdx.y + j];
}

__global__ __launch_bounds__(128) void cos_k(const float* __restrict__ P,
                                             const float* __restrict__ Yn,
                                             float* __restrict__ cb) {
  int r = blockIdx.x, tid = threadIdx.x;
  float4 p = ((const float4*)(P + (size_t)r * D))[tid];
  float4 y = ((const float4*)(Yn + (size_t)r * D))[tid];
  float d  = p.x * y.x + p.y * y.y + p.z * y.z + p.w * y.w;
  float np = p.x * p.x + p.y * p.y + p.z * p.z + p.w * p.w;
  float ny = y.x * y.x + y.y * y.y + y.z * y.z + y.w * y.w;
  d = wave_reduce(d);
  np = wave_reduce(np);
  ny = wave_reduce(ny);
  __shared__ float sh[6];
  int lane = tid & 63, wid = tid >> 6;
  if (lane == 0) { sh[wid] = d; sh[2 + wid] = np; sh[4 + wid] = ny; }
  __syncthreads();
  if (tid == 0) {
    float dt = sh[0] + sh[1], npt = sh[2] + sh[3], nyt = sh[4] + sh[5];
    cb[r] = dt / (fmaxf(sqrtf(npt), 1e-8f) * fmaxf(sqrtf(nyt), 1e-8f));
  }
}

__global__ __launch_bounds__(256) void mean_k(const float* __restrict__ cb,
                                              float* __restrict__ out) {
  int tid = threadIdx.x;
  float s = cb[tid] + cb[tid + 256] + cb[tid + 512] + cb[tid + 768];
  s = wave_reduce(s);
  __shared__ float sh[4];
  int lane = tid & 63, wid = tid >> 6;
  if (lane == 0) sh[wid] = s;
  __syncthreads();
  if (tid == 0) out[0] = (sh[0] + sh[1] + sh[2] + sh[3]) * (1.0f / (float)N);
}

// ---------------- host orchestration ----------------
extern "C" void kernel_launch(void* const* d_in, const int* in_sizes, int n_in,
                              void* d_out, int out_size, void* d_ws, size_t ws_size,
                              hipStream_t stream) {
  const float* fea1 = (const float*)d_in[0];
  const float* fea2 = (const float*)d_in[1];
  float* ws = (float*)d_ws;
  float* Yn  = ws;                              // N*D
  float* An  = Yn + (size_t)N * D;              // N*D
  float* Mm  = An + (size_t)N * D;              // N*N
  float* YAt = Mm + (size_t)N * N;              // N*N
  float* Xg  = YAt + (size_t)N * N;             // N*N
  float* Vp0 = Xg + (size_t)N * N;              // N*N
  float* Vp1 = Vp0 + (size_t)N * N;             // N*N
  unsigned short* Zint = (unsigned short*)(Vp1 + (size_t)N * N);  // N*N pairs
  unsigned short* Mint = Zint + 2 * (size_t)N * N;
  float* vb    = (float*)(Mint + 2 * (size_t)N * N);  // 3*N
  float* stepP = vb + 3 * N;
  float* AnT = Vp0;                     // D*N (dead-buffer reuse after loop)
  float* P   = Vp0 + (size_t)N * D;     // N*D
  float* cosb = Mm;

  normalize_k<<<2 * N, 256, 0, stream>>>(fea1, fea2, Yn, An);
  gemm_nt<<<dim3(N / 64, N / 64), 256, 0, stream>>>(An, D, An, D, Mm, N, D);
  gemm_nt<<<dim3(N / 64, N / 64), 256, 0, stream>>>(Yn, D, An, D, YAt, N, D);

  // ---- try cooperative persistent path; fall back to multi-kernel ----
  bool coop = false;
  {
    int maxb = 0;
    if (hipOccupancyMaxActiveBlocksPerMultiprocessor(
            &maxb, (const void*)fista_persistent, 256, 0) == hipSuccess) {
      hipDeviceProp_t prop;
      int dev = 0;
      hipGetDevice(&dev);
      if (hipGetDeviceProperties(&prop, dev) == hipSuccess)
        coop = ((long)maxb * prop.multiProcessorCount >= 512);
    }
  }
  if (coop) {
    const float* Mm_ = Mm;
    unsigned short *Zint_ = Zint, *Mint_ = Mint;
    const float* YAt_ = YAt;
    float *Vp0_ = Vp0, *Vp1_ = Vp1, *vb_ = vb, *stepP_ = stepP, *Xg_ = Xg;
    void* kargs[] = {(void*)&Mm_, (void*)&Zint_, (void*)&Mint_, (void*)&YAt_,
                     (void*)&Vp0_, (void*)&Vp1_, (void*)&vb_, (void*)&stepP_,
                     (void*)&Xg_};
    hipError_t e = hipLaunchCooperativeKernel((const void*)fista_persistent,
                                              dim3(512), dim3(256), kargs, 0,
                                              stream);
    if (e != hipSuccess) {
      (void)hipGetLastError();  // clear sticky error
      coop = false;
    }
  }
  if (!coop) {
    split_int_k<<<(N * N) / 2048, 256, 0, stream>>>(Mm, Mint);
    init_int_k<<<N, 256, 0, stream>>>(Xg, Zint, vb);
    float* pv = vb;
    float* pw = vb + N;
    for (int i = 0; i < PIT; ++i) {
      matvec_k<<<N / 4, 256, 0, stream>>>(Mm, pv, pw, 0.125f);
      float* t = pv; pv = pw; pw = t;
    }
    matvec_k<<<N / 4, 256, 0, stream>>>(Mm, pv, pw, 1.0f);
    rayleigh_k<<<1, 256, 0, stream>>>(pv, pw, stepP);
    float t = 1.0f;
    for (int it = 0; it < NIT; ++it) {
      fista_gemm_fb<<<dim3(N / 64, N / 64, 2), 256, 0, stream>>>(Zint, Mint,
                                                                 Vp0);
      float tn = 0.5f * (1.0f + sqrtf(1.0f + 4.0f * t * t));
      float mom = (t - 1.0f) / tn;
      t = tn;
      fista_update_fb<<<N, 256, 0, stream>>>(Vp0, Vp1, YAt, stepP, Xg, Zint,
                                             mom);
    }
  }

  transpose_k<<<dim3(D / 32, N / 32), dim3(32, 8), 0, stream>>>(An, AnT);
  gemm_nt<<<dim3(D / 64, N / 64), 256, 0, stream>>>(Xg, N, AnT, N, P, D, N);
  cos_k<<<N, 128, 0, stream>>>(P, Yn, cosb);
  mean_k<<<1, 256, 0, stream>>>(cosb, (float*)d_out);
}